// Round 15
// baseline (435.327 us; speedup 1.0000x reference)
//
#include <hip/hip_runtime.h>
#include <hip/hip_bf16.h>
#include <math.h>

#define NNODES 10000
#define NEDGES 160000
#define EDIM   256
#define HIDC   128
#define TLEN   64
#define VOCAB  50257
#define NEG    0.2f
#define NCTXSLOT 32

typedef __bf16 bf16x8 __attribute__((ext_vector_type(8)));
typedef float  f32x4  __attribute__((ext_vector_type(4)));

static __device__ __forceinline__ float leaky(float x){ return x > 0.f ? x : NEG*x; }
static __device__ __forceinline__ float sigm (float x){ return __fdividef(1.f, 1.f + __expf(-x)); }
static __device__ __forceinline__ float eluf (float x){ return x > 0.f ? x : expm1f(x); }
static __device__ __forceinline__ unsigned short bf16rn(float f){
  unsigned a = __float_as_uint(f);
  return (unsigned short)((a + 0x7FFFu + ((a >> 16) & 1u)) >> 16);
}
static __device__ __forceinline__ float upf(unsigned short u){ return __uint_as_float(((unsigned)u) << 16); }
static __device__ __forceinline__ float4 up4(ushort4 u){
  float4 f; f.x = upf(u.x); f.y = upf(u.y); f.z = upf(u.z); f.w = upf(u.w); return f;
}
static __device__ __forceinline__ float bflo(unsigned w){ return __uint_as_float(w << 16); }
static __device__ __forceinline__ float bfhi(unsigned w){ return __uint_as_float(w & 0xFFFF0000u); }
// fp8 e4m3 (OCP) helpers via gfx950 HW cvt
static __device__ __forceinline__ unsigned char fp8e4m3(float f){
  return (unsigned char)(__builtin_amdgcn_cvt_pk_fp8_f32(f, f, 0, false) & 0xFF);
}
static __device__ __forceinline__ float4 up8x4(unsigned d){  // 4 packed fp8 -> 4 f32
  auto lo = __builtin_amdgcn_cvt_pk_f32_fp8((int)d, false);
  auto hi = __builtin_amdgcn_cvt_pk_f32_fp8((int)d, true);
  float4 f; f.x = lo[0]; f.y = lo[1]; f.z = hi[0]; f.w = hi[1]; return f;
}

// ---------------- fused prep kernel ----------------
#define PB_FEATS 2500
#define PB_WCAST 8783
#define PB_TR1L  8815
#define PB_TR1R  8847
#define PB_TR2L  8863
#define PB_TR2R  8879
#define PB_ZERO  8919
#define PB_AT    9047

static __device__ void tr_dev(const float* __restrict__ in, unsigned short* __restrict__ out,
                              int K, int Nin, int bx, int by, int t,
                              unsigned short (*tile)[72])
{
  int k0 = bx*64, n0 = by*64;
  int tr = t >> 4, tc4 = (t & 15)*4;
  #pragma unroll
  for (int it = 0; it < 4; ++it){
    int kr = tr + 16*it;
    float4 v = *(const float4*)(in + (size_t)(k0+kr)*Nin + n0 + tc4);
    tile[tc4+0][kr] = bf16rn(v.x);
    tile[tc4+1][kr] = bf16rn(v.y);
    tile[tc4+2][kr] = bf16rn(v.z);
    tile[tc4+3][kr] = bf16rn(v.w);
  }
  __syncthreads();
  #pragma unroll
  for (int it = 0; it < 4; ++it){
    int nr = tr + 16*it;
    ushort4 o;
    o.x = tile[nr][tc4+0]; o.y = tile[nr][tc4+1];
    o.z = tile[nr][tc4+2]; o.w = tile[nr][tc4+3];
    *(ushort4*)(out + (size_t)(n0+nr)*K + k0 + tc4) = o;
  }
}

__global__ __launch_bounds__(256) void k_prep(
    const int* __restrict__ xn, const float* __restrict__ emb,
    unsigned short* __restrict__ featsb,
    const float* __restrict__ Wout, unsigned short* __restrict__ Woutb,
    const float* __restrict__ W1l, const float* __restrict__ W1r, unsigned short* __restrict__ Bt1,
    const float* __restrict__ W2l, const float* __restrict__ W2r, unsigned short* __restrict__ Bt2,
    int* __restrict__ deg, int* __restrict__ cursor, float* __restrict__ ctxp,
    const int* __restrict__ tseq, const float* __restrict__ Wih,
    const float* __restrict__ bih, float* __restrict__ At, int* __restrict__ done)
{
  __shared__ unsigned short tile[64][72];
  __shared__ __align__(16) float xe[EDIM];
  int b = blockIdx.x, t = threadIdx.x;
  if (b < PB_FEATS){
    int node = b*4 + (t >> 6);
    int l = t & 63;
    float4 v = ((const float4*)(emb + (size_t)xn[node]*EDIM))[l];
    ushort4 o; o.x = bf16rn(v.x); o.y = bf16rn(v.y); o.z = bf16rn(v.z); o.w = bf16rn(v.w);
    *(ushort4*)(featsb + (size_t)node*EDIM + 4*l) = o;
  } else if (b < PB_WCAST){
    int idx = (b - PB_FEATS)*256 + t;
    if (idx < VOCAB*HIDC/4){
      float4 v = ((const float4*)Wout)[idx];
      ushort4 o; o.x = bf16rn(v.x); o.y = bf16rn(v.y); o.z = bf16rn(v.z); o.w = bf16rn(v.w);
      ((ushort4*)Woutb)[idx] = o;
    }
  } else if (b < PB_TR1L){
    int lb = b - PB_WCAST;  tr_dev(W1l, Bt1,           256, 512, lb & 3, lb >> 2, t, tile);
  } else if (b < PB_TR1R){
    int lb = b - PB_TR1L;   tr_dev(W1r, Bt1 + 512*256, 256, 512, lb & 3, lb >> 2, t, tile);
  } else if (b < PB_TR2L){
    int lb = b - PB_TR1R;   tr_dev(W2l, Bt2,           512, 128, lb & 7, lb >> 3, t, tile);
  } else if (b < PB_TR2R){
    int lb = b - PB_TR2L;   tr_dev(W2r, Bt2 + 128*512, 512, 128, lb & 7, lb >> 3, t, tile);
  } else if (b < PB_ZERO){
    int gid = (b - PB_TR2R)*256 + t;
    if (gid < NNODES){ deg[gid] = 0; cursor[gid] = 0; }
    if (gid < NCTXSLOT*HIDC) ctxp[gid] = 0.f;
    if (gid == 0) *done = 0;
  } else {
    // At[t][row] = bih[row] + Wih[row, 0:256] . emb[tok_t]
    int lb = b - PB_ZERO;           // 0..127
    int tt = lb >> 1;               // 0..63
    int row = (lb & 1)*192 + t;     // two blocks per t, 192 rows each
    int tok = (tt == 0) ? 0 : tseq[tt-1];
    { // stage emb row in LDS (256 floats)
      if (t < 64) ((float4*)xe)[t] = ((const float4*)(emb + (size_t)tok*EDIM))[t];
      __syncthreads();
    }
    if (t < 192){
      const float4* w4 = (const float4*)(Wih + (size_t)row*384);
      const float4* x4 = (const float4*)xe;
      float a0 = 0.f, a1 = 0.f, a2 = 0.f, a3 = 0.f;
      #pragma unroll
      for (int k = 0; k < 64; k++){
        float4 w = w4[k]; float4 x = x4[k];
        a0 = fmaf(w.x, x.x, a0); a1 = fmaf(w.y, x.y, a1);
        a2 = fmaf(w.z, x.z, a2); a3 = fmaf(w.w, x.w, a3);
      }
      At[tt*384 + row] = ((a0 + a1) + (a2 + a3)) + bih[row];
    }
  }
}

// ---------------- CSR build ----------------
__global__ void k_deg(const int* __restrict__ dst, int* __restrict__ deg){
  int e = blockIdx.x*256 + threadIdx.x;
  if (e < NEDGES) atomicAdd(&deg[dst[e]], 1);
}

__global__ __launch_bounds__(1024) void k_scan(const int* __restrict__ deg, int* __restrict__ offs){
  __shared__ int s[1024];
  int t = threadIdx.x;
  int loc[10]; int sum = 0;
  #pragma unroll
  for (int q = 0; q < 10; q++){
    int idx = t*10 + q;
    loc[q] = sum;
    sum += (idx < NNODES) ? deg[idx] : 0;
  }
  s[t] = sum;
  __syncthreads();
  for (int ofs = 1; ofs < 1024; ofs <<= 1){
    int v = (t >= ofs) ? s[t-ofs] : 0;
    __syncthreads();
    s[t] += v;
    __syncthreads();
  }
  int pre = (t > 0) ? s[t-1] : 0;
  #pragma unroll
  for (int q = 0; q < 10; q++){
    int idx = t*10 + q;
    if (idx < NNODES) offs[idx] = pre + loc[q];
  }
  if (t == 1023) offs[NNODES] = s[1023];
}

__global__ void k_scatter(const int* __restrict__ src, const int* __restrict__ dst,
                          const int* __restrict__ offs, int* __restrict__ cursor,
                          int* __restrict__ esrc){
  int e = blockIdx.x*256 + threadIdx.x;
  if (e >= NEDGES) return;
  int d = dst[e];
  int p = atomicAdd(&cursor[d], 1);
  esrc[offs[d] + p] = src[e];
}

// ---------------- bf16 MFMA GEMM: [C0|C1] = A[M,K] @ Bt[N,K]^T ----------------
// C cols [0,N/2) -> C0 fp8 (gathered operand), cols [N/2,N) -> C1 bf16.
template<int KDIM>
__global__ __launch_bounds__(256) void k_mfma(const unsigned short* __restrict__ A,
    const unsigned short* __restrict__ Bt,
    unsigned char* __restrict__ C0, unsigned short* __restrict__ C1,
    int M, int N)
{
  __shared__ __align__(16) unsigned short As[128*64];
  __shared__ __align__(16) unsigned short Bs[128*64];
  int tid = threadIdx.x;
  int l   = tid & 63;
  int wid = tid >> 6;
  int wr = wid >> 1, wc = wid & 1;
  int row0 = blockIdx.x * 128, col0 = blockIdx.y * 128;
  int lr = l & 15, kg = l >> 4;
  f32x4 acc[4][4] = {};

  for (int kt = 0; kt < KDIM/64; ++kt){
    int k0 = kt*64;
    #pragma unroll
    for (int c = 0; c < 4; ++c){
      int chunk = wid*4 + c;                       // 0..15, 8 rows each
      int arow = row0 + chunk*8 + (l >> 3);
      if (arow > M-1) arow = M-1;
      const unsigned short* ga = A + (size_t)arow*KDIM + k0 + (l & 7)*8;
      __builtin_amdgcn_global_load_lds(
          (const __attribute__((address_space(1))) void*)ga,
          (__attribute__((address_space(3))) void*)(As + chunk*512), 16, 0, 0);
      int brow = col0 + chunk*8 + (l >> 3);        // N is a multiple of 128
      const unsigned short* gb = Bt + (size_t)brow*KDIM + k0 + (l & 7)*8;
      __builtin_amdgcn_global_load_lds(
          (const __attribute__((address_space(1))) void*)gb,
          (__attribute__((address_space(3))) void*)(Bs + chunk*512), 16, 0, 0);
    }
    __syncthreads();
    #pragma unroll
    for (int ks = 0; ks < 2; ++ks){
      bf16x8 af[4], bfr[4];
      #pragma unroll
      for (int m = 0; m < 4; ++m)
        af[m] = *(const bf16x8*)(As + (wr*64 + m*16 + lr)*64 + ks*32 + kg*8);
      #pragma unroll
      for (int n = 0; n < 4; ++n)
        bfr[n] = *(const bf16x8*)(Bs + (wc*64 + n*16 + lr)*64 + ks*32 + kg*8);
      #pragma unroll
      for (int m = 0; m < 4; ++m)
        #pragma unroll
        for (int n = 0; n < 4; ++n)
          acc[m][n] = __builtin_amdgcn_mfma_f32_16x16x32_bf16(af[m], bfr[n], acc[m][n], 0, 0, 0);
    }
    __syncthreads();
  }

  int half = N >> 1;
  bool isXL = (col0 < half);
  int cb = isXL ? col0 : col0 - half;
  #pragma unroll
  for (int m = 0; m < 4; ++m){
    int rbase = row0 + wr*64 + m*16 + kg*4;
    #pragma unroll
    for (int r = 0; r < 4; ++r){
      int row = rbase + r;
      if (row < M){
        #pragma unroll
        for (int n = 0; n < 4; ++n){
          int col = cb + wc*64 + n*16 + lr;
          if (isXL) C0[(size_t)row*half + col] = fp8e4m3(acc[m][n][r]);
          else      C1[(size_t)row*half + col] = bf16rn(acc[m][n][r]);
        }
      }
    }
  }
}

// ---------------- output projection: out[t][v] = HTt[t,:]·Woutb[v,:] + bout[v] ----------------
__global__ __launch_bounds__(256) void k_mout(const unsigned short* __restrict__ A,
    const unsigned short* __restrict__ Bt, const float* __restrict__ bias,
    float* __restrict__ out)
{
  __shared__ __align__(16) unsigned short As[64*128];
  __shared__ __align__(16) unsigned short Bs[128*128];
  int tid = threadIdx.x;
  int l   = tid & 63;
  int wid = tid >> 6;
  int col0 = blockIdx.x * 128;
  int lr = l & 15, kg = l >> 4;

  #pragma unroll
  for (int c = 0; c < 4; ++c){
    int chunk = wid*4 + c;
    const unsigned short* ga = A + (size_t)(chunk*4 + (l >> 4))*128 + (l & 15)*8;
    __builtin_amdgcn_global_load_lds(
        (const __attribute__((address_space(1))) void*)ga,
        (__attribute__((address_space(3))) void*)(As + chunk*512), 16, 0, 0);
  }
  #pragma unroll
  for (int c = 0; c < 8; ++c){
    int chunk = wid*8 + c;
    int brow = col0 + chunk*4 + (l >> 4);
    if (brow > VOCAB-1) brow = VOCAB-1;
    const unsigned short* gb = Bt + (size_t)brow*128 + (l & 15)*8;
    __builtin_amdgcn_global_load_lds(
        (const __attribute__((address_space(1))) void*)gb,
        (__attribute__((address_space(3))) void*)(Bs + chunk*512), 16, 0, 0);
  }
  __syncthreads();

  f32x4 acc[4][2] = {};
  #pragma unroll
  for (int ks = 0; ks < 4; ++ks){
    bf16x8 af[4], bfr[2];
    #pragma unroll
    for (int m = 0; m < 4; ++m)
      af[m] = *(const bf16x8*)(As + (m*16 + lr)*128 + ks*32 + kg*8);
    #pragma unroll
    for (int n = 0; n < 2; ++n)
      bfr[n] = *(const bf16x8*)(Bs + (wid*32 + n*16 + lr)*128 + ks*32 + kg*8);
    #pragma unroll
    for (int m = 0; m < 4; ++m)
      #pragma unroll
      for (int n = 0; n < 2; ++n)
        acc[m][n] = __builtin_amdgcn_mfma_f32_16x16x32_bf16(af[m], bfr[n], acc[m][n], 0, 0, 0);
  }

  #pragma unroll
  for (int n = 0; n < 2; ++n){
    int col = col0 + wid*32 + n*16 + lr;
    if (col < VOCAB){
      float bv = bias[col];
      #pragma unroll
      for (int m = 0; m < 4; ++m){
        #pragma unroll
        for (int r = 0; r < 4; ++r){
          int trow = m*16 + kg*4 + r;              // t in 0..63
          out[(size_t)trow*VOCAB + col] = acc[m][n][r] + bv;
        }
      }
    }
  }
}

// ---------------- GAT layer 1 (heads=4, 128ch), fp8 xl gather, 1-edge pipeline ----------------
__global__ __launch_bounds__(256) void k_gat1(const unsigned char* __restrict__ xl,
    const unsigned short* __restrict__ xr,
    const int* __restrict__ esrc, const int* __restrict__ offs,
    const float* __restrict__ att, const float* __restrict__ b1,
    unsigned short* __restrict__ h1b)
{
  int node = blockIdx.x*4 + (threadIdx.x >> 6);
  int l = threadIdx.x & 63;
  const unsigned short* ri = xr + (size_t)node*512;
  float4 xr1 = up4(*(const ushort4*)(ri + 4*l));
  float4 xr2 = up4(*(const ushort4*)(ri + 256 + 4*l));
  int hq = l >> 5;
  float4 at1 = *(const float4*)(att + hq*HIDC + ((4*l) & 127));
  float4 at2 = *(const float4*)(att + (2+hq)*HIDC + ((4*l) & 127));
  float4 ac1 = {0,0,0,0}, ac2 = {0,0,0,0};
  float d1 = 0.f, d2 = 0.f;
  int beg = offs[node], end = offs[node+1];
  int sB = (beg < end) ? esrc[beg] : 0;
  const unsigned char* rA = xl + (size_t)node*512;
  unsigned dA0 = *(const unsigned*)(rA + 4*l);
  unsigned dA1 = *(const unsigned*)(rA + 256 + 4*l);
  for (int p = beg-1; p < end; ++p){
    const unsigned char* rB = xl + (size_t)sB*512;
    unsigned dB0 = *(const unsigned*)(rB + 4*l);
    unsigned dB1 = *(const unsigned*)(rB + 256 + 4*l);
    int sC = (p+2 < end) ? esrc[p+2] : 0;
    float4 x1 = up8x4(dA0);
    float4 x2 = up8x4(dA1);
    float p1 = leaky(x1.x+xr1.x)*at1.x + leaky(x1.y+xr1.y)*at1.y
             + leaky(x1.z+xr1.z)*at1.z + leaky(x1.w+xr1.w)*at1.w;
    float p2 = leaky(x2.x+xr2.x)*at2.x + leaky(x2.y+xr2.y)*at2.y
             + leaky(x2.z+xr2.z)*at2.z + leaky(x2.w+xr2.w)*at2.w;
    #pragma unroll
    for (int m = 1; m <= 16; m <<= 1){
      p1 += __shfl_xor(p1, m);
      p2 += __shfl_xor(p2, m);
    }
    float w1 = __expf(p1), w2 = __expf(p2);
    ac1.x = fmaf(w1, x1.x, ac1.x); ac1.y = fmaf(w1, x1.y, ac1.y);
    ac1.z = fmaf(w1, x1.z, ac1.z); ac1.w = fmaf(w1, x1.w, ac1.w);
    ac2.x = fmaf(w2, x2.x, ac2.x); ac2.y = fmaf(w2, x2.y, ac2.y);
    ac2.z = fmaf(w2, x2.z, ac2.z); ac2.w = fmaf(w2, x2.w, ac2.w);
    d1 += w1; d2 += w2;
    dA0 = dB0; dA1 = dB1; sB = sC;
  }
  float i1 = 1.f/d1, i2 = 1.f/d2;
  const float* bq1 = b1 + 4*l;
  const float* bq2 = b1 + 256 + 4*l;
  ushort4 o1, o2;
  o1.x = bf16rn(eluf(ac1.x*i1 + bq1[0])); o1.y = bf16rn(eluf(ac1.y*i1 + bq1[1]));
  o1.z = bf16rn(eluf(ac1.z*i1 + bq1[2])); o1.w = bf16rn(eluf(ac1.w*i1 + bq1[3]));
  o2.x = bf16rn(eluf(ac2.x*i2 + bq2[0])); o2.y = bf16rn(eluf(ac2.y*i2 + bq2[1]));
  o2.z = bf16rn(eluf(ac2.z*i2 + bq2[2])); o2.w = bf16rn(eluf(ac2.w*i2 + bq2[3]));
  *(ushort4*)(h1b + (size_t)node*512 + 4*l)       = o1;
  *(ushort4*)(h1b + (size_t)node*512 + 256 + 4*l) = o2;
}

// ---------------- GAT layer 2 + fused graph-mean + last-block ctx/Gi ----------------
// After the per-block ctxp partial add, the LAST block (device-scope counter) sums
// the 32 slots and writes Gi = At + Wih[:,256:384].(ctx+b2) -- replaces k_ctx node.
__global__ __launch_bounds__(256) void k_gat2(const unsigned char* __restrict__ xl,
    const unsigned short* __restrict__ xr,
    const int* __restrict__ esrc, const int* __restrict__ offs,
    const float* __restrict__ att2, float* __restrict__ ctxp,
    const float* __restrict__ At, const float* __restrict__ b2,
    const float* __restrict__ Wih, float* __restrict__ Gi, int* __restrict__ done)
{
  __shared__ float csum[128];
  int node = blockIdx.x*4 + (threadIdx.x >> 6);
  int l = threadIdx.x & 63;
  if (threadIdx.x < 128) csum[threadIdx.x] = 0.f;
  __syncthreads();
  ushort2 v = *(const ushort2*)(xr + (size_t)node*128 + 2*l);
  float2 xrv; xrv.x = upf(v.x); xrv.y = upf(v.y);
  float2 at = *(const float2*)(att2 + 2*l);
  float2 ac = {0,0}; float den = 0.f;
  int beg = offs[node], end = offs[node+1];
  int sB = (beg < end) ? esrc[beg] : 0;
  unsigned short uA = *(const unsigned short*)(xl + (size_t)node*128 + 2*l);
  for (int p = beg-1; p < end; ++p){
    unsigned short uB = *(const unsigned short*)(xl + (size_t)sB*128 + 2*l);
    int sC = (p+2 < end) ? esrc[p+2] : 0;
    auto xv = __builtin_amdgcn_cvt_pk_f32_fp8((int)(unsigned)uA, false);
    float2 x; x.x = xv[0]; x.y = xv[1];
    float pp = leaky(x.x+xrv.x)*at.x + leaky(x.y+xrv.y)*at.y;
    #pragma unroll
    for (int m = 1; m <= 32; m <<= 1) pp += __shfl_xor(pp, m);
    float w = __expf(pp);
    ac.x = fmaf(w, x.x, ac.x); ac.y = fmaf(w, x.y, ac.y);
    den += w;
    uA = uB; sB = sC;
  }
  float inv = 1.f/den;
  atomicAdd(&csum[2*l],   ac.x*inv);
  atomicAdd(&csum[2*l+1], ac.y*inv);
  __syncthreads();
  if (threadIdx.x < 128)
    atomicAdd(&ctxp[(blockIdx.x & (NCTXSLOT-1))*HIDC + threadIdx.x],
              csum[threadIdx.x] * (1.f/NNODES));

  // ----- last-block ctx reduction + Gi write (replaces k_ctx) -----
  __threadfence();
  __shared__ int lastFlag;
  if (threadIdx.x == 0)
    lastFlag = (atomicAdd(done, 1) == (int)gridDim.x - 1);
  __syncthreads();
  if (!lastFlag) return;

  __shared__ __align__(16) float CTX[128];
  if (threadIdx.x < 128){
    float s = 0.f;
    #pragma unroll
    for (int j = 0; j < NCTXSLOT; ++j)
      s += __hip_atomic_load(&ctxp[j*HIDC + threadIdx.x], __ATOMIC_RELAXED,
                             __HIP_MEMORY_SCOPE_AGENT);
    CTX[threadIdx.x] = s + b2[threadIdx.x];
  }
  __syncthreads();
  for (int row = threadIdx.x; row < 384; row += 256){
    const float4* wi = (const float4*)(Wih + (size_t)row*384 + 256);
    const float4* c4 = (const float4*)CTX;
    float a0 = 0.f, a1 = 0.f, a2 = 0.f, a3 = 0.f;
    #pragma unroll
    for (int k = 0; k < 32; k++){
      float4 ww = wi[k]; float4 cc = c4[k];
      a0 = fmaf(ww.x, cc.x, a0); a1 = fmaf(ww.y, cc.y, a1);
      a2 = fmaf(ww.z, cc.z, a2); a3 = fmaf(ww.w, cc.w, a3);
    }
    float c = ((a0 + a1) + (a2 + a3));
    for (int t = 0; t < TLEN; t++)
      Gi[t*384 + row] = At[t*384 + row] + c;
  }
}

// ---------------- GRU recurrence (R8 core; h stored bf16 in LDS -> half the
// LDS-broadcast instructions, which R5 measured as the bottleneck) ----------------
__global__ __launch_bounds__(384) void k_gru(const float* __restrict__ Gi,
    const float* __restrict__ Whh, const float* __restrict__ bhh,
    unsigned short* __restrict__ HTt)
{
  __shared__ float GH[384];
  __shared__ alignas(16) unsigned short HSu[128];
  int tid = threadIdx.x;
  float w[128];
  {
    const float4* wrow = (const float4*)(Whh + (size_t)tid*HIDC);
    #pragma unroll
    for (int k = 0; k < 32; k++){
      float4 v = wrow[k];
      w[4*k+0] = v.x; w[4*k+1] = v.y; w[4*k+2] = v.z; w[4*k+3] = v.w;
    }
  }
  float bh = bhh[tid];
  float hloc = 0.f;
  if (tid < 128) HSu[tid] = 0;
  __syncthreads();

  const uint4* H4 = (const uint4*)HSu;

  for (int t = 0; t < TLEN; t++){
    float gi0 = 0.f, gi1 = 0.f, gi2 = 0.f;
    if (tid < 128){
      gi0 = Gi[t*384 + tid];
      gi1 = Gi[t*384 + 128 + tid];
      gi2 = Gi[t*384 + 256 + tid];
    }
    float a0 = 0.f, a1 = 0.f, a2 = 0.f, a3 = 0.f;
    #pragma unroll
    for (int q = 0; q < 16; q++){
      uint4 d = H4[q];                      // h[8q..8q+7] as packed bf16
      a0 = fmaf(w[8*q+0], bflo(d.x), a0);
      a1 = fmaf(w[8*q+1], bfhi(d.x), a1);
      a2 = fmaf(w[8*q+2], bflo(d.y), a2);
      a3 = fmaf(w[8*q+3], bfhi(d.y), a3);
      a0 = fmaf(w[8*q+4], bflo(d.z), a0);
      a1 = fmaf(w[8*q+5], bfhi(d.z), a1);
      a2 = fmaf(w[8*q+6], bflo(d.w), a2);
      a3 = fmaf(w[8*q+7], bfhi(d.w), a3);
    }
    float acc = ((a0 + a1) + (a2 + a3)) + bh;
    if (tid >= 128) GH[tid] = acc;
    __syncthreads();
    if (tid < 128){
      float gr = gi0 + acc;
      float gz = gi1 + GH[128 + tid];
      float hn = GH[256 + tid];
      float r = sigm(gr);
      float z = sigm(gz);
      float e2 = __expf(2.f*(gi2 + r*hn));
      float cand = __fdividef(e2 - 1.f, e2 + 1.f);
      float hnew = (1.f - z)*cand + z*hloc;
      hloc = hnew;
      unsigned short ush = bf16rn(hnew);
      HSu[tid] = ush;
      HTt[t*HIDC + tid] = ush;
    }
    __syncthreads();
  }
}

// ---------------- launch ----------------
extern "C" void kernel_launch(void* const* d_in, const int* in_sizes, int n_in,
                              void* d_out, int out_size, void* d_ws, size_t ws_size,
                              hipStream_t stream)
{
  const int*   x_nodes = (const int*)  d_in[0];
  const int*   eidx    = (const int*)  d_in[1];   // [2][160000]: src then dst
  const int*   tseq    = (const int*)  d_in[2];
  const float* emb     = (const float*)d_in[3];
  const float* W1l     = (const float*)d_in[4];
  const float* W1r     = (const float*)d_in[5];
  const float* att1    = (const float*)d_in[6];
  const float* b1      = (const float*)d_in[7];
  const float* W2l     = (const float*)d_in[8];
  const float* W2r     = (const float*)d_in[9];
  const float* att2    = (const float*)d_in[10];
  const float* b2      = (const float*)d_in[11];
  const float* Wih     = (const float*)d_in[12];
  const float* Whh     = (const float*)d_in[13];
  const float* bih     = (const float*)d_in[14];
  const float* bhh     = (const float*)d_in[15];
  const float* Wout    = (const float*)d_in[16];
  const float* bout    = (const float*)d_in[17];
  float* out = (float*)d_out;
  char*  ws  = (char*)d_ws;

  // workspace layout (bytes), no aliasing
  unsigned char*  xl1f8  = (unsigned char*) (ws);              // 10000*512   =  5,120,000
  unsigned short* xr1b   = (unsigned short*)(ws + 5120000);    // 10000*512*2 = 10,240,000
  unsigned short* h1b    = (unsigned short*)(ws + 15360000);   // 10000*512*2 = 10,240,000
  unsigned short* featsb = (unsigned short*)(ws + 25600000);   // 10000*256*2 =  5,120,000
  unsigned char*  xl2f8  = (unsigned char*) (ws + 30720000);   // 10000*128   =  1,280,000
  unsigned short* xr2b   = (unsigned short*)(ws + 32000000);   // 10000*128*2 =  2,560,000
  unsigned short* Bt1    = (unsigned short*)(ws + 34560000);   // 1024*256*2  =    524,288
  unsigned short* Bt2    = (unsigned short*)(ws + 35084288);   // 256*512*2   =    262,144
  int*   deg    = (int*)(ws + 35346432);                       // 40,000
  int*   offs   = (int*)(ws + 35386432);                       // 40,004
  int*   cursor = (int*)(ws + 35426436);                       // 40,000
  int*   esrc   = (int*)(ws + 35466436);                       // 640,000 (ends 36,106,436)
  float* At     = (float*)(ws + 36106496);                     // 64*384*4 = 98,304 (ends 36,204,800)
  unsigned short* HTt   = (unsigned short*)(ws + 36204800);    // 64*128*2 = 16,384
  unsigned short* Woutb = (unsigned short*)(ws + 36221184);    // 12,865,792 (ends 49,086,976)
  float* ctxp   = (float*)(ws + 49086976);                     // 32*128*4 = 16,384 (ends 49,103,360)
  int*   done   = (int*)  (ws + 49103360);                     // 4 (pad to 64)
  float* Gi     = (float*)(ws + 49103424);                     // 64*384*4 = 98,304 (ends 49,201,728)

  k_prep<<<PB_AT, 256, 0, stream>>>(x_nodes, emb, featsb, Wout, Woutb,
                                    W1l, W1r, Bt1, W2l, W2r, Bt2,
                                    deg, cursor, ctxp, tseq, Wih, bih, At, done);

  k_deg    <<<625, 256, 0, stream>>>(eidx + NEDGES, deg);
  k_scan   <<<1,  1024, 0, stream>>>(deg, offs);
  k_scatter<<<625, 256, 0, stream>>>(eidx, eidx + NEDGES, offs, cursor, esrc);

  k_mfma<256><<<dim3(79,8), 256, 0, stream>>>(featsb, Bt1, xl1f8, xr1b, NNODES, 1024);
  k_gat1<<<2500, 256, 0, stream>>>(xl1f8, xr1b, esrc, offs, att1, b1, h1b);

  k_mfma<512><<<dim3(79,2), 256, 0, stream>>>(h1b, Bt2, xl2f8, xr2b, NNODES, 256);
  k_gat2<<<2500, 256, 0, stream>>>(xl2f8, xr2b, esrc, offs, att2, ctxp,
                                   At, b2, Wih, Gi, done);

  k_gru<<<1, 384, 0, stream>>>(Gi, Whh, bhh, HTt);

  k_mout<<<393, 256, 0, stream>>>(HTt, Woutb, bout, out);
}

// Round 16
// 249.432 us; speedup vs baseline: 1.7453x; 1.7453x over previous
//
#include <hip/hip_runtime.h>
#include <hip/hip_bf16.h>
#include <math.h>

#define NNODES 10000
#define NEDGES 160000
#define EDIM   256
#define HIDC   128
#define TLEN   64
#define VOCAB  50257
#define NEG    0.2f
#define NCTXSLOT 32

typedef __bf16 bf16x8 __attribute__((ext_vector_type(8)));
typedef float  f32x4  __attribute__((ext_vector_type(4)));

static __device__ __forceinline__ float leaky(float x){ return x > 0.f ? x : NEG*x; }
static __device__ __forceinline__ float sigm (float x){ return __fdividef(1.f, 1.f + __expf(-x)); }
static __device__ __forceinline__ float eluf (float x){ return x > 0.f ? x : expm1f(x); }
static __device__ __forceinline__ unsigned short bf16rn(float f){
  unsigned a = __float_as_uint(f);
  return (unsigned short)((a + 0x7FFFu + ((a >> 16) & 1u)) >> 16);
}
static __device__ __forceinline__ float upf(unsigned short u){ return __uint_as_float(((unsigned)u) << 16); }
static __device__ __forceinline__ float4 up4(ushort4 u){
  float4 f; f.x = upf(u.x); f.y = upf(u.y); f.z = upf(u.z); f.w = upf(u.w); return f;
}
static __device__ __forceinline__ float bflo(unsigned w){ return __uint_as_float(w << 16); }
static __device__ __forceinline__ float bfhi(unsigned w){ return __uint_as_float(w & 0xFFFF0000u); }
// fp8 e4m3 (OCP) helpers via gfx950 HW cvt
static __device__ __forceinline__ unsigned char fp8e4m3(float f){
  return (unsigned char)(__builtin_amdgcn_cvt_pk_fp8_f32(f, f, 0, false) & 0xFF);
}
static __device__ __forceinline__ float4 up8x4(unsigned d){  // 4 packed fp8 -> 4 f32
  auto lo = __builtin_amdgcn_cvt_pk_f32_fp8((int)d, false);
  auto hi = __builtin_amdgcn_cvt_pk_f32_fp8((int)d, true);
  float4 f; f.x = lo[0]; f.y = lo[1]; f.z = hi[0]; f.w = hi[1]; return f;
}

// ---------------- fused prep kernel ----------------
#define PB_FEATS 2500
#define PB_WCAST 8783
#define PB_TR1L  8815
#define PB_TR1R  8847
#define PB_TR2L  8863
#define PB_TR2R  8879
#define PB_ZERO  8919
#define PB_AT    9047

static __device__ void tr_dev(const float* __restrict__ in, unsigned short* __restrict__ out,
                              int K, int Nin, int bx, int by, int t,
                              unsigned short (*tile)[72])
{
  int k0 = bx*64, n0 = by*64;
  int tr = t >> 4, tc4 = (t & 15)*4;
  #pragma unroll
  for (int it = 0; it < 4; ++it){
    int kr = tr + 16*it;
    float4 v = *(const float4*)(in + (size_t)(k0+kr)*Nin + n0 + tc4);
    tile[tc4+0][kr] = bf16rn(v.x);
    tile[tc4+1][kr] = bf16rn(v.y);
    tile[tc4+2][kr] = bf16rn(v.z);
    tile[tc4+3][kr] = bf16rn(v.w);
  }
  __syncthreads();
  #pragma unroll
  for (int it = 0; it < 4; ++it){
    int nr = tr + 16*it;
    ushort4 o;
    o.x = tile[nr][tc4+0]; o.y = tile[nr][tc4+1];
    o.z = tile[nr][tc4+2]; o.w = tile[nr][tc4+3];
    *(ushort4*)(out + (size_t)(n0+nr)*K + k0 + tc4) = o;
  }
}

__global__ __launch_bounds__(256) void k_prep(
    const int* __restrict__ xn, const float* __restrict__ emb,
    unsigned short* __restrict__ featsb,
    const float* __restrict__ Wout, unsigned short* __restrict__ Woutb,
    const float* __restrict__ W1l, const float* __restrict__ W1r, unsigned short* __restrict__ Bt1,
    const float* __restrict__ W2l, const float* __restrict__ W2r, unsigned short* __restrict__ Bt2,
    int* __restrict__ deg, int* __restrict__ cursor, float* __restrict__ ctxp,
    const int* __restrict__ tseq, const float* __restrict__ Wih,
    const float* __restrict__ bih, float* __restrict__ At)
{
  __shared__ unsigned short tile[64][72];
  __shared__ __align__(16) float xe[EDIM];
  int b = blockIdx.x, t = threadIdx.x;
  if (b < PB_FEATS){
    int node = b*4 + (t >> 6);
    int l = t & 63;
    float4 v = ((const float4*)(emb + (size_t)xn[node]*EDIM))[l];
    ushort4 o; o.x = bf16rn(v.x); o.y = bf16rn(v.y); o.z = bf16rn(v.z); o.w = bf16rn(v.w);
    *(ushort4*)(featsb + (size_t)node*EDIM + 4*l) = o;
  } else if (b < PB_WCAST){
    int idx = (b - PB_FEATS)*256 + t;
    if (idx < VOCAB*HIDC/4){
      float4 v = ((const float4*)Wout)[idx];
      ushort4 o; o.x = bf16rn(v.x); o.y = bf16rn(v.y); o.z = bf16rn(v.z); o.w = bf16rn(v.w);
      ((ushort4*)Woutb)[idx] = o;
    }
  } else if (b < PB_TR1L){
    int lb = b - PB_WCAST;  tr_dev(W1l, Bt1,           256, 512, lb & 3, lb >> 2, t, tile);
  } else if (b < PB_TR1R){
    int lb = b - PB_TR1L;   tr_dev(W1r, Bt1 + 512*256, 256, 512, lb & 3, lb >> 2, t, tile);
  } else if (b < PB_TR2L){
    int lb = b - PB_TR1R;   tr_dev(W2l, Bt2,           512, 128, lb & 7, lb >> 3, t, tile);
  } else if (b < PB_TR2R){
    int lb = b - PB_TR2L;   tr_dev(W2r, Bt2 + 128*512, 512, 128, lb & 7, lb >> 3, t, tile);
  } else if (b < PB_ZERO){
    int gid = (b - PB_TR2R)*256 + t;
    if (gid < NNODES){ deg[gid] = 0; cursor[gid] = 0; }
    if (gid < NCTXSLOT*HIDC) ctxp[gid] = 0.f;
  } else {
    // At[t][row] = bih[row] + Wih[row, 0:256] . emb[tok_t]
    int lb = b - PB_ZERO;           // 0..127
    int tt = lb >> 1;               // 0..63
    int row = (lb & 1)*192 + t;     // two blocks per t, 192 rows each
    int tok = (tt == 0) ? 0 : tseq[tt-1];
    { // stage emb row in LDS (256 floats)
      if (t < 64) ((float4*)xe)[t] = ((const float4*)(emb + (size_t)tok*EDIM))[t];
      __syncthreads();
    }
    if (t < 192){
      const float4* w4 = (const float4*)(Wih + (size_t)row*384);
      const float4* x4 = (const float4*)xe;
      float a0 = 0.f, a1 = 0.f, a2 = 0.f, a3 = 0.f;
      #pragma unroll
      for (int k = 0; k < 64; k++){
        float4 w = w4[k]; float4 x = x4[k];
        a0 = fmaf(w.x, x.x, a0); a1 = fmaf(w.y, x.y, a1);
        a2 = fmaf(w.z, x.z, a2); a3 = fmaf(w.w, x.w, a3);
      }
      At[tt*384 + row] = ((a0 + a1) + (a2 + a3)) + bih[row];
    }
  }
}

// ---------------- CSR build ----------------
__global__ void k_deg(const int* __restrict__ dst, int* __restrict__ deg){
  int e = blockIdx.x*256 + threadIdx.x;
  if (e < NEDGES) atomicAdd(&deg[dst[e]], 1);
}

__global__ __launch_bounds__(1024) void k_scan(const int* __restrict__ deg, int* __restrict__ offs){
  __shared__ int s[1024];
  int t = threadIdx.x;
  int loc[10]; int sum = 0;
  #pragma unroll
  for (int q = 0; q < 10; q++){
    int idx = t*10 + q;
    loc[q] = sum;
    sum += (idx < NNODES) ? deg[idx] : 0;
  }
  s[t] = sum;
  __syncthreads();
  for (int ofs = 1; ofs < 1024; ofs <<= 1){
    int v = (t >= ofs) ? s[t-ofs] : 0;
    __syncthreads();
    s[t] += v;
    __syncthreads();
  }
  int pre = (t > 0) ? s[t-1] : 0;
  #pragma unroll
  for (int q = 0; q < 10; q++){
    int idx = t*10 + q;
    if (idx < NNODES) offs[idx] = pre + loc[q];
  }
  if (t == 1023) offs[NNODES] = s[1023];
}

__global__ void k_scatter(const int* __restrict__ src, const int* __restrict__ dst,
                          const int* __restrict__ offs, int* __restrict__ cursor,
                          int* __restrict__ esrc){
  int e = blockIdx.x*256 + threadIdx.x;
  if (e >= NEDGES) return;
  int d = dst[e];
  int p = atomicAdd(&cursor[d], 1);
  esrc[offs[d] + p] = src[e];
}

// ---------------- bf16 MFMA GEMM: [C0|C1] = A[M,K] @ Bt[N,K]^T ----------------
// C cols [0,N/2) -> C0 fp8 (gathered operand), cols [N/2,N) -> C1 bf16.
template<int KDIM>
__global__ __launch_bounds__(256) void k_mfma(const unsigned short* __restrict__ A,
    const unsigned short* __restrict__ Bt,
    unsigned char* __restrict__ C0, unsigned short* __restrict__ C1,
    int M, int N)
{
  __shared__ __align__(16) unsigned short As[128*64];
  __shared__ __align__(16) unsigned short Bs[128*64];
  int tid = threadIdx.x;
  int l   = tid & 63;
  int wid = tid >> 6;
  int wr = wid >> 1, wc = wid & 1;
  int row0 = blockIdx.x * 128, col0 = blockIdx.y * 128;
  int lr = l & 15, kg = l >> 4;
  f32x4 acc[4][4] = {};

  for (int kt = 0; kt < KDIM/64; ++kt){
    int k0 = kt*64;
    #pragma unroll
    for (int c = 0; c < 4; ++c){
      int chunk = wid*4 + c;                       // 0..15, 8 rows each
      int arow = row0 + chunk*8 + (l >> 3);
      if (arow > M-1) arow = M-1;
      const unsigned short* ga = A + (size_t)arow*KDIM + k0 + (l & 7)*8;
      __builtin_amdgcn_global_load_lds(
          (const __attribute__((address_space(1))) void*)ga,
          (__attribute__((address_space(3))) void*)(As + chunk*512), 16, 0, 0);
      int brow = col0 + chunk*8 + (l >> 3);        // N is a multiple of 128
      const unsigned short* gb = Bt + (size_t)brow*KDIM + k0 + (l & 7)*8;
      __builtin_amdgcn_global_load_lds(
          (const __attribute__((address_space(1))) void*)gb,
          (__attribute__((address_space(3))) void*)(Bs + chunk*512), 16, 0, 0);
    }
    __syncthreads();
    #pragma unroll
    for (int ks = 0; ks < 2; ++ks){
      bf16x8 af[4], bfr[4];
      #pragma unroll
      for (int m = 0; m < 4; ++m)
        af[m] = *(const bf16x8*)(As + (wr*64 + m*16 + lr)*64 + ks*32 + kg*8);
      #pragma unroll
      for (int n = 0; n < 4; ++n)
        bfr[n] = *(const bf16x8*)(Bs + (wc*64 + n*16 + lr)*64 + ks*32 + kg*8);
      #pragma unroll
      for (int m = 0; m < 4; ++m)
        #pragma unroll
        for (int n = 0; n < 4; ++n)
          acc[m][n] = __builtin_amdgcn_mfma_f32_16x16x32_bf16(af[m], bfr[n], acc[m][n], 0, 0, 0);
    }
    __syncthreads();
  }

  int half = N >> 1;
  bool isXL = (col0 < half);
  int cb = isXL ? col0 : col0 - half;
  #pragma unroll
  for (int m = 0; m < 4; ++m){
    int rbase = row0 + wr*64 + m*16 + kg*4;
    #pragma unroll
    for (int r = 0; r < 4; ++r){
      int row = rbase + r;
      if (row < M){
        #pragma unroll
        for (int n = 0; n < 4; ++n){
          int col = cb + wc*64 + n*16 + lr;
          if (isXL) C0[(size_t)row*half + col] = fp8e4m3(acc[m][n][r]);
          else      C1[(size_t)row*half + col] = bf16rn(acc[m][n][r]);
        }
      }
    }
  }
}

// ---------------- output projection: out[t][v] = HTt[t,:]·Woutb[v,:] + bout[v] ----------------
__global__ __launch_bounds__(256) void k_mout(const unsigned short* __restrict__ A,
    const unsigned short* __restrict__ Bt, const float* __restrict__ bias,
    float* __restrict__ out)
{
  __shared__ __align__(16) unsigned short As[64*128];
  __shared__ __align__(16) unsigned short Bs[128*128];
  int tid = threadIdx.x;
  int l   = tid & 63;
  int wid = tid >> 6;
  int col0 = blockIdx.x * 128;
  int lr = l & 15, kg = l >> 4;

  #pragma unroll
  for (int c = 0; c < 4; ++c){
    int chunk = wid*4 + c;
    const unsigned short* ga = A + (size_t)(chunk*4 + (l >> 4))*128 + (l & 15)*8;
    __builtin_amdgcn_global_load_lds(
        (const __attribute__((address_space(1))) void*)ga,
        (__attribute__((address_space(3))) void*)(As + chunk*512), 16, 0, 0);
  }
  #pragma unroll
  for (int c = 0; c < 8; ++c){
    int chunk = wid*8 + c;
    int brow = col0 + chunk*4 + (l >> 4);
    if (brow > VOCAB-1) brow = VOCAB-1;
    const unsigned short* gb = Bt + (size_t)brow*128 + (l & 15)*8;
    __builtin_amdgcn_global_load_lds(
        (const __attribute__((address_space(1))) void*)gb,
        (__attribute__((address_space(3))) void*)(Bs + chunk*512), 16, 0, 0);
  }
  __syncthreads();

  f32x4 acc[4][2] = {};
  #pragma unroll
  for (int ks = 0; ks < 4; ++ks){
    bf16x8 af[4], bfr[2];
    #pragma unroll
    for (int m = 0; m < 4; ++m)
      af[m] = *(const bf16x8*)(As + (m*16 + lr)*128 + ks*32 + kg*8);
    #pragma unroll
    for (int n = 0; n < 2; ++n)
      bfr[n] = *(const bf16x8*)(Bs + (wid*32 + n*16 + lr)*128 + ks*32 + kg*8);
    #pragma unroll
    for (int m = 0; m < 4; ++m)
      #pragma unroll
      for (int n = 0; n < 2; ++n)
        acc[m][n] = __builtin_amdgcn_mfma_f32_16x16x32_bf16(af[m], bfr[n], acc[m][n], 0, 0, 0);
  }

  #pragma unroll
  for (int n = 0; n < 2; ++n){
    int col = col0 + wid*32 + n*16 + lr;
    if (col < VOCAB){
      float bv = bias[col];
      #pragma unroll
      for (int m = 0; m < 4; ++m){
        #pragma unroll
        for (int r = 0; r < 4; ++r){
          int trow = m*16 + kg*4 + r;              // t in 0..63
          out[(size_t)trow*VOCAB + col] = acc[m][n][r] + bv;
        }
      }
    }
  }
}

// ---------------- GAT layer 1 (heads=4, 128ch), fp8 xl gather, 1-edge pipeline ----------------
__global__ __launch_bounds__(256) void k_gat1(const unsigned char* __restrict__ xl,
    const unsigned short* __restrict__ xr,
    const int* __restrict__ esrc, const int* __restrict__ offs,
    const float* __restrict__ att, const float* __restrict__ b1,
    unsigned short* __restrict__ h1b)
{
  int node = blockIdx.x*4 + (threadIdx.x >> 6);
  int l = threadIdx.x & 63;
  const unsigned short* ri = xr + (size_t)node*512;
  float4 xr1 = up4(*(const ushort4*)(ri + 4*l));
  float4 xr2 = up4(*(const ushort4*)(ri + 256 + 4*l));
  int hq = l >> 5;
  float4 at1 = *(const float4*)(att + hq*HIDC + ((4*l) & 127));
  float4 at2 = *(const float4*)(att + (2+hq)*HIDC + ((4*l) & 127));
  float4 ac1 = {0,0,0,0}, ac2 = {0,0,0,0};
  float d1 = 0.f, d2 = 0.f;
  int beg = offs[node], end = offs[node+1];
  int sB = (beg < end) ? esrc[beg] : 0;
  const unsigned char* rA = xl + (size_t)node*512;
  unsigned dA0 = *(const unsigned*)(rA + 4*l);
  unsigned dA1 = *(const unsigned*)(rA + 256 + 4*l);
  for (int p = beg-1; p < end; ++p){
    const unsigned char* rB = xl + (size_t)sB*512;
    unsigned dB0 = *(const unsigned*)(rB + 4*l);
    unsigned dB1 = *(const unsigned*)(rB + 256 + 4*l);
    int sC = (p+2 < end) ? esrc[p+2] : 0;
    float4 x1 = up8x4(dA0);
    float4 x2 = up8x4(dA1);
    float p1 = leaky(x1.x+xr1.x)*at1.x + leaky(x1.y+xr1.y)*at1.y
             + leaky(x1.z+xr1.z)*at1.z + leaky(x1.w+xr1.w)*at1.w;
    float p2 = leaky(x2.x+xr2.x)*at2.x + leaky(x2.y+xr2.y)*at2.y
             + leaky(x2.z+xr2.z)*at2.z + leaky(x2.w+xr2.w)*at2.w;
    #pragma unroll
    for (int m = 1; m <= 16; m <<= 1){
      p1 += __shfl_xor(p1, m);
      p2 += __shfl_xor(p2, m);
    }
    float w1 = __expf(p1), w2 = __expf(p2);
    ac1.x = fmaf(w1, x1.x, ac1.x); ac1.y = fmaf(w1, x1.y, ac1.y);
    ac1.z = fmaf(w1, x1.z, ac1.z); ac1.w = fmaf(w1, x1.w, ac1.w);
    ac2.x = fmaf(w2, x2.x, ac2.x); ac2.y = fmaf(w2, x2.y, ac2.y);
    ac2.z = fmaf(w2, x2.z, ac2.z); ac2.w = fmaf(w2, x2.w, ac2.w);
    d1 += w1; d2 += w2;
    dA0 = dB0; dA1 = dB1; sB = sC;
  }
  float i1 = 1.f/d1, i2 = 1.f/d2;
  const float* bq1 = b1 + 4*l;
  const float* bq2 = b1 + 256 + 4*l;
  ushort4 o1, o2;
  o1.x = bf16rn(eluf(ac1.x*i1 + bq1[0])); o1.y = bf16rn(eluf(ac1.y*i1 + bq1[1]));
  o1.z = bf16rn(eluf(ac1.z*i1 + bq1[2])); o1.w = bf16rn(eluf(ac1.w*i1 + bq1[3]));
  o2.x = bf16rn(eluf(ac2.x*i2 + bq2[0])); o2.y = bf16rn(eluf(ac2.y*i2 + bq2[1]));
  o2.z = bf16rn(eluf(ac2.z*i2 + bq2[2])); o2.w = bf16rn(eluf(ac2.w*i2 + bq2[3]));
  *(ushort4*)(h1b + (size_t)node*512 + 4*l)       = o1;
  *(ushort4*)(h1b + (size_t)node*512 + 256 + 4*l) = o2;
}

// ---------------- GAT layer 2 (R14 version: pure gather + slotted mean) ----------------
__global__ __launch_bounds__(256) void k_gat2(const unsigned char* __restrict__ xl,
    const unsigned short* __restrict__ xr,
    const int* __restrict__ esrc, const int* __restrict__ offs,
    const float* __restrict__ att2, float* __restrict__ ctxp)
{
  __shared__ float csum[128];
  int node = blockIdx.x*4 + (threadIdx.x >> 6);
  int l = threadIdx.x & 63;
  if (threadIdx.x < 128) csum[threadIdx.x] = 0.f;
  __syncthreads();
  ushort2 v = *(const ushort2*)(xr + (size_t)node*128 + 2*l);
  float2 xrv; xrv.x = upf(v.x); xrv.y = upf(v.y);
  float2 at = *(const float2*)(att2 + 2*l);
  float2 ac = {0,0}; float den = 0.f;
  int beg = offs[node], end = offs[node+1];
  int sB = (beg < end) ? esrc[beg] : 0;
  unsigned short uA = *(const unsigned short*)(xl + (size_t)node*128 + 2*l);
  for (int p = beg-1; p < end; ++p){
    unsigned short uB = *(const unsigned short*)(xl + (size_t)sB*128 + 2*l);
    int sC = (p+2 < end) ? esrc[p+2] : 0;
    auto xv = __builtin_amdgcn_cvt_pk_f32_fp8((int)(unsigned)uA, false);
    float2 x; x.x = xv[0]; x.y = xv[1];
    float pp = leaky(x.x+xrv.x)*at.x + leaky(x.y+xrv.y)*at.y;
    #pragma unroll
    for (int m = 1; m <= 32; m <<= 1) pp += __shfl_xor(pp, m);
    float w = __expf(pp);
    ac.x = fmaf(w, x.x, ac.x); ac.y = fmaf(w, x.y, ac.y);
    den += w;
    uA = uB; sB = sC;
  }
  float inv = 1.f/den;
  atomicAdd(&csum[2*l],   ac.x*inv);
  atomicAdd(&csum[2*l+1], ac.y*inv);
  __syncthreads();
  if (threadIdx.x < 128)
    atomicAdd(&ctxp[(blockIdx.x & (NCTXSLOT-1))*HIDC + threadIdx.x],
              csum[threadIdx.x] * (1.f/NNODES));
}

// ---------------- k_ctx: Gi[t] = At[t] + Wih[:,256:384].(sum ctxp + b2) ----------------
__global__ __launch_bounds__(384) void k_ctx(const float* __restrict__ At,
    const float* __restrict__ ctxp, const float* __restrict__ b2,
    const float* __restrict__ Wih, float* __restrict__ Gi)
{
  __shared__ alignas(16) float CTX[128];
  int tid = threadIdx.x;
  if (tid < 128){
    float s = 0.f;
    #pragma unroll
    for (int j = 0; j < NCTXSLOT; ++j) s += ctxp[j*HIDC + tid];
    CTX[tid] = s + b2[tid];
  }
  __syncthreads();
  const float4* wi = (const float4*)(Wih + (size_t)tid*384 + 256);
  const float4* c4 = (const float4*)CTX;
  float a0 = 0.f, a1 = 0.f, a2 = 0.f, a3 = 0.f;
  #pragma unroll
  for (int k = 0; k < 32; k++){
    float4 ww = wi[k]; float4 cc = c4[k];
    a0 = fmaf(ww.x, cc.x, a0); a1 = fmaf(ww.y, cc.y, a1);
    a2 = fmaf(ww.z, cc.z, a2); a3 = fmaf(ww.w, cc.w, a3);
  }
  float c = ((a0 + a1) + (a2 + a3));
  for (int t = 0; t < TLEN; t++)
    Gi[t*384 + tid] = At[t*384 + tid] + c;
}

// ---------------- GRU recurrence (R8 core; h stored bf16 in LDS -> half the
// LDS-broadcast instructions, which R5 measured as the bottleneck) ----------------
__global__ __launch_bounds__(384) void k_gru(const float* __restrict__ Gi,
    const float* __restrict__ Whh, const float* __restrict__ bhh,
    unsigned short* __restrict__ HTt)
{
  __shared__ float GH[384];
  __shared__ alignas(16) unsigned short HSu[128];
  int tid = threadIdx.x;
  float w[128];
  {
    const float4* wrow = (const float4*)(Whh + (size_t)tid*HIDC);
    #pragma unroll
    for (int k = 0; k < 32; k++){
      float4 v = wrow[k];
      w[4*k+0] = v.x; w[4*k+1] = v.y; w[4*k+2] = v.z; w[4*k+3] = v.w;
    }
  }
  float bh = bhh[tid];
  float hloc = 0.f;
  if (tid < 128) HSu[tid] = 0;
  __syncthreads();

  const uint4* H4 = (const uint4*)HSu;

  for (int t = 0; t < TLEN; t++){
    float gi0 = 0.f, gi1 = 0.f, gi2 = 0.f;
    if (tid < 128){
      gi0 = Gi[t*384 + tid];
      gi1 = Gi[t*384 + 128 + tid];
      gi2 = Gi[t*384 + 256 + tid];
    }
    float a0 = 0.f, a1 = 0.f, a2 = 0.f, a3 = 0.f;
    #pragma unroll
    for (int q = 0; q < 16; q++){
      uint4 d = H4[q];                      // h[8q..8q+7] as packed bf16
      a0 = fmaf(w[8*q+0], bflo(d.x), a0);
      a1 = fmaf(w[8*q+1], bfhi(d.x), a1);
      a2 = fmaf(w[8*q+2], bflo(d.y), a2);
      a3 = fmaf(w[8*q+3], bfhi(d.y), a3);
      a0 = fmaf(w[8*q+4], bflo(d.z), a0);
      a1 = fmaf(w[8*q+5], bfhi(d.z), a1);
      a2 = fmaf(w[8*q+6], bflo(d.w), a2);
      a3 = fmaf(w[8*q+7], bfhi(d.w), a3);
    }
    float acc = ((a0 + a1) + (a2 + a3)) + bh;
    if (tid >= 128) GH[tid] = acc;
    __syncthreads();
    if (tid < 128){
      float gr = gi0 + acc;
      float gz = gi1 + GH[128 + tid];
      float hn = GH[256 + tid];
      float r = sigm(gr);
      float z = sigm(gz);
      float e2 = __expf(2.f*(gi2 + r*hn));
      float cand = __fdividef(e2 - 1.f, e2 + 1.f);
      float hnew = (1.f - z)*cand + z*hloc;
      hloc = hnew;
      unsigned short ush = bf16rn(hnew);
      HSu[tid] = ush;
      HTt[t*HIDC + tid] = ush;
    }
    __syncthreads();
  }
}

// ---------------- launch ----------------
extern "C" void kernel_launch(void* const* d_in, const int* in_sizes, int n_in,
                              void* d_out, int out_size, void* d_ws, size_t ws_size,
                              hipStream_t stream)
{
  const int*   x_nodes = (const int*)  d_in[0];
  const int*   eidx    = (const int*)  d_in[1];   // [2][160000]: src then dst
  const int*   tseq    = (const int*)  d_in[2];
  const float* emb     = (const float*)d_in[3];
  const float* W1l     = (const float*)d_in[4];
  const float* W1r     = (const float*)d_in[5];
  const float* att1    = (const float*)d_in[6];
  const float* b1      = (const float*)d_in[7];
  const float* W2l     = (const float*)d_in[8];
  const float* W2r     = (const float*)d_in[9];
  const float* att2    = (const float*)d_in[10];
  const float* b2      = (const float*)d_in[11];
  const float* Wih     = (const float*)d_in[12];
  const float* Whh     = (const float*)d_in[13];
  const float* bih     = (const float*)d_in[14];
  const float* bhh     = (const float*)d_in[15];
  const float* Wout    = (const float*)d_in[16];
  const float* bout    = (const float*)d_in[17];
  float* out = (float*)d_out;
  char*  ws  = (char*)d_ws;

  // workspace layout (bytes), no aliasing
  unsigned char*  xl1f8  = (unsigned char*) (ws);              // 10000*512   =  5,120,000
  unsigned short* xr1b   = (unsigned short*)(ws + 5120000);    // 10000*512*2 = 10,240,000
  unsigned short* h1b    = (unsigned short*)(ws + 15360000);   // 10000*512*2 = 10,240,000
  unsigned short* featsb = (unsigned short*)(ws + 25600000);   // 10000*256*2 =  5,120,000
  unsigned char*  xl2f8  = (unsigned char*) (ws + 30720000);   // 10000*128   =  1,280,000
  unsigned short* xr2b   = (unsigned short*)(ws + 32000000);   // 10000*128*2 =  2,560,000
  unsigned short* Bt1    = (unsigned short*)(ws + 34560000);   // 1024*256*2  =    524,288
  unsigned short* Bt2    = (unsigned short*)(ws + 35084288);   // 256*512*2   =    262,144
  int*   deg    = (int*)(ws + 35346432);                       // 40,000
  int*   offs   = (int*)(ws + 35386432);                       // 40,004
  int*   cursor = (int*)(ws + 35426436);                       // 40,000
  int*   esrc   = (int*)(ws + 35466436);                       // 640,000 (ends 36,106,436)
  float* At     = (float*)(ws + 36106496);                     // 64*384*4 = 98,304 (ends 36,204,800)
  unsigned short* HTt   = (unsigned short*)(ws + 36204800);    // 64*128*2 = 16,384
  unsigned short* Woutb = (unsigned short*)(ws + 36221184);    // 12,865,792 (ends 49,086,976)
  float* ctxp   = (float*)(ws + 49086976);                     // 32*128*4 = 16,384 (ends 49,103,360)
  float* Gi     = (float*)(ws + 49103424);                     // 64*384*4 = 98,304 (ends 49,201,728)

  k_prep<<<PB_AT, 256, 0, stream>>>(x_nodes, emb, featsb, Wout, Woutb,
                                    W1l, W1r, Bt1, W2l, W2r, Bt2,
                                    deg, cursor, ctxp, tseq, Wih, bih, At);

  k_deg    <<<625, 256, 0, stream>>>(eidx + NEDGES, deg);
  k_scan   <<<1,  1024, 0, stream>>>(deg, offs);
  k_scatter<<<625, 256, 0, stream>>>(eidx, eidx + NEDGES, offs, cursor, esrc);

  k_mfma<256><<<dim3(79,8), 256, 0, stream>>>(featsb, Bt1, xl1f8, xr1b, NNODES, 1024);
  k_gat1<<<2500, 256, 0, stream>>>(xl1f8, xr1b, esrc, offs, att1, b1, h1b);

  k_mfma<512><<<dim3(79,2), 256, 0, stream>>>(h1b, Bt2, xl2f8, xr2b, NNODES, 256);
  k_gat2<<<2500, 256, 0, stream>>>(xl2f8, xr2b, esrc, offs, att2, ctxp);

  k_ctx<<<1, 384, 0, stream>>>(At, ctxp, b2, Wih, Gi);
  k_gru<<<1, 384, 0, stream>>>(Gi, Whh, bhh, HTt);

  k_mout<<<393, 256, 0, stream>>>(HTt, Woutb, bout, out);
}

// Round 17
// 242.056 us; speedup vs baseline: 1.7985x; 1.0305x over previous
//
#include <hip/hip_runtime.h>
#include <hip/hip_bf16.h>
#include <math.h>

#define NNODES 10000
#define NEDGES 160000
#define EDIM   256
#define HIDC   128
#define TLEN   64
#define VOCAB  50257
#define NEG    0.2f
#define NCTXSLOT 32

typedef __bf16 bf16x8 __attribute__((ext_vector_type(8)));
typedef float  f32x4  __attribute__((ext_vector_type(4)));

static __device__ __forceinline__ float leaky(float x){ return x > 0.f ? x : NEG*x; }
static __device__ __forceinline__ float sigm (float x){ return __fdividef(1.f, 1.f + __expf(-x)); }
static __device__ __forceinline__ float eluf (float x){ return x > 0.f ? x : expm1f(x); }
static __device__ __forceinline__ unsigned short bf16rn(float f){
  unsigned a = __float_as_uint(f);
  return (unsigned short)((a + 0x7FFFu + ((a >> 16) & 1u)) >> 16);
}
static __device__ __forceinline__ float upf(unsigned short u){ return __uint_as_float(((unsigned)u) << 16); }
static __device__ __forceinline__ float4 up4(ushort4 u){
  float4 f; f.x = upf(u.x); f.y = upf(u.y); f.z = upf(u.z); f.w = upf(u.w); return f;
}
// fp8 e4m3 (OCP) helpers via gfx950 HW cvt
static __device__ __forceinline__ unsigned char fp8e4m3(float f){
  return (unsigned char)(__builtin_amdgcn_cvt_pk_fp8_f32(f, f, 0, false) & 0xFF);
}
static __device__ __forceinline__ float4 up8x4(unsigned d){  // 4 packed fp8 -> 4 f32
  auto lo = __builtin_amdgcn_cvt_pk_f32_fp8((int)d, false);
  auto hi = __builtin_amdgcn_cvt_pk_f32_fp8((int)d, true);
  float4 f; f.x = lo[0]; f.y = lo[1]; f.z = hi[0]; f.w = hi[1]; return f;
}

// ---------------- fused prep kernel ----------------
#define PB_FEATS 2500
#define PB_WCAST 8783
#define PB_TR1L  8815
#define PB_TR1R  8847
#define PB_TR2L  8863
#define PB_TR2R  8879
#define PB_ZERO  8919
#define PB_AT    9047

static __device__ void tr_dev(const float* __restrict__ in, unsigned short* __restrict__ out,
                              int K, int Nin, int bx, int by, int t,
                              unsigned short (*tile)[72])
{
  int k0 = bx*64, n0 = by*64;
  int tr = t >> 4, tc4 = (t & 15)*4;
  #pragma unroll
  for (int it = 0; it < 4; ++it){
    int kr = tr + 16*it;
    float4 v = *(const float4*)(in + (size_t)(k0+kr)*Nin + n0 + tc4);
    tile[tc4+0][kr] = bf16rn(v.x);
    tile[tc4+1][kr] = bf16rn(v.y);
    tile[tc4+2][kr] = bf16rn(v.z);
    tile[tc4+3][kr] = bf16rn(v.w);
  }
  __syncthreads();
  #pragma unroll
  for (int it = 0; it < 4; ++it){
    int nr = tr + 16*it;
    ushort4 o;
    o.x = tile[nr][tc4+0]; o.y = tile[nr][tc4+1];
    o.z = tile[nr][tc4+2]; o.w = tile[nr][tc4+3];
    *(ushort4*)(out + (size_t)(n0+nr)*K + k0 + tc4) = o;
  }
}

__global__ __launch_bounds__(256) void k_prep(
    const int* __restrict__ xn, const float* __restrict__ emb,
    unsigned short* __restrict__ featsb,
    const float* __restrict__ Wout, unsigned short* __restrict__ Woutb,
    const float* __restrict__ W1l, const float* __restrict__ W1r, unsigned short* __restrict__ Bt1,
    const float* __restrict__ W2l, const float* __restrict__ W2r, unsigned short* __restrict__ Bt2,
    int* __restrict__ deg, int* __restrict__ cursor, float* __restrict__ ctxp,
    const int* __restrict__ tseq, const float* __restrict__ Wih,
    const float* __restrict__ bih, float* __restrict__ At)
{
  __shared__ unsigned short tile[64][72];
  __shared__ __align__(16) float xe[EDIM];
  int b = blockIdx.x, t = threadIdx.x;
  if (b < PB_FEATS){
    int node = b*4 + (t >> 6);
    int l = t & 63;
    float4 v = ((const float4*)(emb + (size_t)xn[node]*EDIM))[l];
    ushort4 o; o.x = bf16rn(v.x); o.y = bf16rn(v.y); o.z = bf16rn(v.z); o.w = bf16rn(v.w);
    *(ushort4*)(featsb + (size_t)node*EDIM + 4*l) = o;
  } else if (b < PB_WCAST){
    int idx = (b - PB_FEATS)*256 + t;
    if (idx < VOCAB*HIDC/4){
      float4 v = ((const float4*)Wout)[idx];
      ushort4 o; o.x = bf16rn(v.x); o.y = bf16rn(v.y); o.z = bf16rn(v.z); o.w = bf16rn(v.w);
      ((ushort4*)Woutb)[idx] = o;
    }
  } else if (b < PB_TR1L){
    int lb = b - PB_WCAST;  tr_dev(W1l, Bt1,           256, 512, lb & 3, lb >> 2, t, tile);
  } else if (b < PB_TR1R){
    int lb = b - PB_TR1L;   tr_dev(W1r, Bt1 + 512*256, 256, 512, lb & 3, lb >> 2, t, tile);
  } else if (b < PB_TR2L){
    int lb = b - PB_TR1R;   tr_dev(W2l, Bt2,           512, 128, lb & 7, lb >> 3, t, tile);
  } else if (b < PB_TR2R){
    int lb = b - PB_TR2L;   tr_dev(W2r, Bt2 + 128*512, 512, 128, lb & 7, lb >> 3, t, tile);
  } else if (b < PB_ZERO){
    int gid = (b - PB_TR2R)*256 + t;
    if (gid < NNODES){ deg[gid] = 0; cursor[gid] = 0; }
    if (gid < NCTXSLOT*HIDC) ctxp[gid] = 0.f;
  } else {
    // At[t][row] = bih[row] + Wih[row, 0:256] . emb[tok_t]
    int lb = b - PB_ZERO;           // 0..127
    int tt = lb >> 1;               // 0..63
    int row = (lb & 1)*192 + t;     // two blocks per t, 192 rows each
    int tok = (tt == 0) ? 0 : tseq[tt-1];
    { // stage emb row in LDS (256 floats)
      if (t < 64) ((float4*)xe)[t] = ((const float4*)(emb + (size_t)tok*EDIM))[t];
      __syncthreads();
    }
    if (t < 192){
      const float4* w4 = (const float4*)(Wih + (size_t)row*384);
      const float4* x4 = (const float4*)xe;
      float a0 = 0.f, a1 = 0.f, a2 = 0.f, a3 = 0.f;
      #pragma unroll
      for (int k = 0; k < 64; k++){
        float4 w = w4[k]; float4 x = x4[k];
        a0 = fmaf(w.x, x.x, a0); a1 = fmaf(w.y, x.y, a1);
        a2 = fmaf(w.z, x.z, a2); a3 = fmaf(w.w, x.w, a3);
      }
      At[tt*384 + row] = ((a0 + a1) + (a2 + a3)) + bih[row];
    }
  }
}

// ---------------- CSR build ----------------
__global__ void k_deg(const int* __restrict__ dst, int* __restrict__ deg){
  int e = blockIdx.x*256 + threadIdx.x;
  if (e < NEDGES) atomicAdd(&deg[dst[e]], 1);
}

__global__ __launch_bounds__(1024) void k_scan(const int* __restrict__ deg, int* __restrict__ offs){
  __shared__ int s[1024];
  int t = threadIdx.x;
  int loc[10]; int sum = 0;
  #pragma unroll
  for (int q = 0; q < 10; q++){
    int idx = t*10 + q;
    loc[q] = sum;
    sum += (idx < NNODES) ? deg[idx] : 0;
  }
  s[t] = sum;
  __syncthreads();
  for (int ofs = 1; ofs < 1024; ofs <<= 1){
    int v = (t >= ofs) ? s[t-ofs] : 0;
    __syncthreads();
    s[t] += v;
    __syncthreads();
  }
  int pre = (t > 0) ? s[t-1] : 0;
  #pragma unroll
  for (int q = 0; q < 10; q++){
    int idx = t*10 + q;
    if (idx < NNODES) offs[idx] = pre + loc[q];
  }
  if (t == 1023) offs[NNODES] = s[1023];
}

__global__ void k_scatter(const int* __restrict__ src, const int* __restrict__ dst,
                          const int* __restrict__ offs, int* __restrict__ cursor,
                          int* __restrict__ esrc){
  int e = blockIdx.x*256 + threadIdx.x;
  if (e >= NEDGES) return;
  int d = dst[e];
  int p = atomicAdd(&cursor[d], 1);
  esrc[offs[d] + p] = src[e];
}

// ---------------- bf16 MFMA GEMM: [C0|C1] = A[M,K] @ Bt[N,K]^T ----------------
// C cols [0,N/2) -> C0 fp8 (gathered operand), cols [N/2,N) -> C1 bf16.
template<int KDIM>
__global__ __launch_bounds__(256) void k_mfma(const unsigned short* __restrict__ A,
    const unsigned short* __restrict__ Bt,
    unsigned char* __restrict__ C0, unsigned short* __restrict__ C1,
    int M, int N)
{
  __shared__ __align__(16) unsigned short As[128*64];
  __shared__ __align__(16) unsigned short Bs[128*64];
  int tid = threadIdx.x;
  int l   = tid & 63;
  int wid = tid >> 6;
  int wr = wid >> 1, wc = wid & 1;
  int row0 = blockIdx.x * 128, col0 = blockIdx.y * 128;
  int lr = l & 15, kg = l >> 4;
  f32x4 acc[4][4] = {};

  for (int kt = 0; kt < KDIM/64; ++kt){
    int k0 = kt*64;
    #pragma unroll
    for (int c = 0; c < 4; ++c){
      int chunk = wid*4 + c;                       // 0..15, 8 rows each
      int arow = row0 + chunk*8 + (l >> 3);
      if (arow > M-1) arow = M-1;
      const unsigned short* ga = A + (size_t)arow*KDIM + k0 + (l & 7)*8;
      __builtin_amdgcn_global_load_lds(
          (const __attribute__((address_space(1))) void*)ga,
          (__attribute__((address_space(3))) void*)(As + chunk*512), 16, 0, 0);
      int brow = col0 + chunk*8 + (l >> 3);        // N is a multiple of 128
      const unsigned short* gb = Bt + (size_t)brow*KDIM + k0 + (l & 7)*8;
      __builtin_amdgcn_global_load_lds(
          (const __attribute__((address_space(1))) void*)gb,
          (__attribute__((address_space(3))) void*)(Bs + chunk*512), 16, 0, 0);
    }
    __syncthreads();
    #pragma unroll
    for (int ks = 0; ks < 2; ++ks){
      bf16x8 af[4], bfr[4];
      #pragma unroll
      for (int m = 0; m < 4; ++m)
        af[m] = *(const bf16x8*)(As + (wr*64 + m*16 + lr)*64 + ks*32 + kg*8);
      #pragma unroll
      for (int n = 0; n < 4; ++n)
        bfr[n] = *(const bf16x8*)(Bs + (wc*64 + n*16 + lr)*64 + ks*32 + kg*8);
      #pragma unroll
      for (int m = 0; m < 4; ++m)
        #pragma unroll
        for (int n = 0; n < 4; ++n)
          acc[m][n] = __builtin_amdgcn_mfma_f32_16x16x32_bf16(af[m], bfr[n], acc[m][n], 0, 0, 0);
    }
    __syncthreads();
  }

  int half = N >> 1;
  bool isXL = (col0 < half);
  int cb = isXL ? col0 : col0 - half;
  #pragma unroll
  for (int m = 0; m < 4; ++m){
    int rbase = row0 + wr*64 + m*16 + kg*4;
    #pragma unroll
    for (int r = 0; r < 4; ++r){
      int row = rbase + r;
      if (row < M){
        #pragma unroll
        for (int n = 0; n < 4; ++n){
          int col = cb + wc*64 + n*16 + lr;
          if (isXL) C0[(size_t)row*half + col] = fp8e4m3(acc[m][n][r]);
          else      C1[(size_t)row*half + col] = bf16rn(acc[m][n][r]);
        }
      }
    }
  }
}

// ---------------- output projection: out[t][v] = HTt[t,:]·Woutb[v,:] + bout[v] ----------------
__global__ __launch_bounds__(256) void k_mout(const unsigned short* __restrict__ A,
    const unsigned short* __restrict__ Bt, const float* __restrict__ bias,
    float* __restrict__ out)
{
  __shared__ __align__(16) unsigned short As[64*128];
  __shared__ __align__(16) unsigned short Bs[128*128];
  int tid = threadIdx.x;
  int l   = tid & 63;
  int wid = tid >> 6;
  int col0 = blockIdx.x * 128;
  int lr = l & 15, kg = l >> 4;

  #pragma unroll
  for (int c = 0; c < 4; ++c){
    int chunk = wid*4 + c;
    const unsigned short* ga = A + (size_t)(chunk*4 + (l >> 4))*128 + (l & 15)*8;
    __builtin_amdgcn_global_load_lds(
        (const __attribute__((address_space(1))) void*)ga,
        (__attribute__((address_space(3))) void*)(As + chunk*512), 16, 0, 0);
  }
  #pragma unroll
  for (int c = 0; c < 8; ++c){
    int chunk = wid*8 + c;
    int brow = col0 + chunk*4 + (l >> 4);
    if (brow > VOCAB-1) brow = VOCAB-1;
    const unsigned short* gb = Bt + (size_t)brow*128 + (l & 15)*8;
    __builtin_amdgcn_global_load_lds(
        (const __attribute__((address_space(1))) void*)gb,
        (__attribute__((address_space(3))) void*)(Bs + chunk*512), 16, 0, 0);
  }
  __syncthreads();

  f32x4 acc[4][2] = {};
  #pragma unroll
  for (int ks = 0; ks < 4; ++ks){
    bf16x8 af[4], bfr[2];
    #pragma unroll
    for (int m = 0; m < 4; ++m)
      af[m] = *(const bf16x8*)(As + (m*16 + lr)*128 + ks*32 + kg*8);
    #pragma unroll
    for (int n = 0; n < 2; ++n)
      bfr[n] = *(const bf16x8*)(Bs + (wid*32 + n*16 + lr)*128 + ks*32 + kg*8);
    #pragma unroll
    for (int m = 0; m < 4; ++m)
      #pragma unroll
      for (int n = 0; n < 2; ++n)
        acc[m][n] = __builtin_amdgcn_mfma_f32_16x16x32_bf16(af[m], bfr[n], acc[m][n], 0, 0, 0);
  }

  #pragma unroll
  for (int n = 0; n < 2; ++n){
    int col = col0 + wid*32 + n*16 + lr;
    if (col < VOCAB){
      float bv = bias[col];
      #pragma unroll
      for (int m = 0; m < 4; ++m){
        #pragma unroll
        for (int r = 0; r < 4; ++r){
          int trow = m*16 + kg*4 + r;              // t in 0..63
          out[(size_t)trow*VOCAB + col] = acc[m][n][r] + bv;
        }
      }
    }
  }
}

// ---------------- GAT layer 1 (heads=4, 128ch), fp8 xl gather, 1-edge pipeline ----------------
__global__ __launch_bounds__(256) void k_gat1(const unsigned char* __restrict__ xl,
    const unsigned short* __restrict__ xr,
    const int* __restrict__ esrc, const int* __restrict__ offs,
    const float* __restrict__ att, const float* __restrict__ b1,
    unsigned short* __restrict__ h1b)
{
  int node = blockIdx.x*4 + (threadIdx.x >> 6);
  int l = threadIdx.x & 63;
  const unsigned short* ri = xr + (size_t)node*512;
  float4 xr1 = up4(*(const ushort4*)(ri + 4*l));
  float4 xr2 = up4(*(const ushort4*)(ri + 256 + 4*l));
  int hq = l >> 5;
  float4 at1 = *(const float4*)(att + hq*HIDC + ((4*l) & 127));
  float4 at2 = *(const float4*)(att + (2+hq)*HIDC + ((4*l) & 127));
  float4 ac1 = {0,0,0,0}, ac2 = {0,0,0,0};
  float d1 = 0.f, d2 = 0.f;
  int beg = offs[node], end = offs[node+1];
  int sB = (beg < end) ? esrc[beg] : 0;
  const unsigned char* rA = xl + (size_t)node*512;
  unsigned dA0 = *(const unsigned*)(rA + 4*l);
  unsigned dA1 = *(const unsigned*)(rA + 256 + 4*l);
  for (int p = beg-1; p < end; ++p){
    const unsigned char* rB = xl + (size_t)sB*512;
    unsigned dB0 = *(const unsigned*)(rB + 4*l);
    unsigned dB1 = *(const unsigned*)(rB + 256 + 4*l);
    int sC = (p+2 < end) ? esrc[p+2] : 0;
    float4 x1 = up8x4(dA0);
    float4 x2 = up8x4(dA1);
    float p1 = leaky(x1.x+xr1.x)*at1.x + leaky(x1.y+xr1.y)*at1.y
             + leaky(x1.z+xr1.z)*at1.z + leaky(x1.w+xr1.w)*at1.w;
    float p2 = leaky(x2.x+xr2.x)*at2.x + leaky(x2.y+xr2.y)*at2.y
             + leaky(x2.z+xr2.z)*at2.z + leaky(x2.w+xr2.w)*at2.w;
    #pragma unroll
    for (int m = 1; m <= 16; m <<= 1){
      p1 += __shfl_xor(p1, m);
      p2 += __shfl_xor(p2, m);
    }
    float w1 = __expf(p1), w2 = __expf(p2);
    ac1.x = fmaf(w1, x1.x, ac1.x); ac1.y = fmaf(w1, x1.y, ac1.y);
    ac1.z = fmaf(w1, x1.z, ac1.z); ac1.w = fmaf(w1, x1.w, ac1.w);
    ac2.x = fmaf(w2, x2.x, ac2.x); ac2.y = fmaf(w2, x2.y, ac2.y);
    ac2.z = fmaf(w2, x2.z, ac2.z); ac2.w = fmaf(w2, x2.w, ac2.w);
    d1 += w1; d2 += w2;
    dA0 = dB0; dA1 = dB1; sB = sC;
  }
  float i1 = 1.f/d1, i2 = 1.f/d2;
  const float* bq1 = b1 + 4*l;
  const float* bq2 = b1 + 256 + 4*l;
  ushort4 o1, o2;
  o1.x = bf16rn(eluf(ac1.x*i1 + bq1[0])); o1.y = bf16rn(eluf(ac1.y*i1 + bq1[1]));
  o1.z = bf16rn(eluf(ac1.z*i1 + bq1[2])); o1.w = bf16rn(eluf(ac1.w*i1 + bq1[3]));
  o2.x = bf16rn(eluf(ac2.x*i2 + bq2[0])); o2.y = bf16rn(eluf(ac2.y*i2 + bq2[1]));
  o2.z = bf16rn(eluf(ac2.z*i2 + bq2[2])); o2.w = bf16rn(eluf(ac2.w*i2 + bq2[3]));
  *(ushort4*)(h1b + (size_t)node*512 + 4*l)       = o1;
  *(ushort4*)(h1b + (size_t)node*512 + 256 + 4*l) = o2;
}

// ---------------- GAT layer 2 (pure gather + slotted mean) ----------------
__global__ __launch_bounds__(256) void k_gat2(const unsigned char* __restrict__ xl,
    const unsigned short* __restrict__ xr,
    const int* __restrict__ esrc, const int* __restrict__ offs,
    const float* __restrict__ att2, float* __restrict__ ctxp)
{
  __shared__ float csum[128];
  int node = blockIdx.x*4 + (threadIdx.x >> 6);
  int l = threadIdx.x & 63;
  if (threadIdx.x < 128) csum[threadIdx.x] = 0.f;
  __syncthreads();
  ushort2 v = *(const ushort2*)(xr + (size_t)node*128 + 2*l);
  float2 xrv; xrv.x = upf(v.x); xrv.y = upf(v.y);
  float2 at = *(const float2*)(att2 + 2*l);
  float2 ac = {0,0}; float den = 0.f;
  int beg = offs[node], end = offs[node+1];
  int sB = (beg < end) ? esrc[beg] : 0;
  unsigned short uA = *(const unsigned short*)(xl + (size_t)node*128 + 2*l);
  for (int p = beg-1; p < end; ++p){
    unsigned short uB = *(const unsigned short*)(xl + (size_t)sB*128 + 2*l);
    int sC = (p+2 < end) ? esrc[p+2] : 0;
    auto xv = __builtin_amdgcn_cvt_pk_f32_fp8((int)(unsigned)uA, false);
    float2 x; x.x = xv[0]; x.y = xv[1];
    float pp = leaky(x.x+xrv.x)*at.x + leaky(x.y+xrv.y)*at.y;
    #pragma unroll
    for (int m = 1; m <= 32; m <<= 1) pp += __shfl_xor(pp, m);
    float w = __expf(pp);
    ac.x = fmaf(w, x.x, ac.x); ac.y = fmaf(w, x.y, ac.y);
    den += w;
    uA = uB; sB = sC;
  }
  float inv = 1.f/den;
  atomicAdd(&csum[2*l],   ac.x*inv);
  atomicAdd(&csum[2*l+1], ac.y*inv);
  __syncthreads();
  if (threadIdx.x < 128)
    atomicAdd(&ctxp[(blockIdx.x & (NCTXSLOT-1))*HIDC + threadIdx.x],
              csum[threadIdx.x] * (1.f/NNODES));
}

// ---------------- k_ctx: Gi[t] = At[t] + Wih[:,256:384].(sum ctxp + b2) ----------------
__global__ __launch_bounds__(384) void k_ctx(const float* __restrict__ At,
    const float* __restrict__ ctxp, const float* __restrict__ b2,
    const float* __restrict__ Wih, float* __restrict__ Gi)
{
  __shared__ alignas(16) float CTX[128];
  int tid = threadIdx.x;
  if (tid < 128){
    float s = 0.f;
    #pragma unroll
    for (int j = 0; j < NCTXSLOT; ++j) s += ctxp[j*HIDC + tid];
    CTX[tid] = s + b2[tid];
  }
  __syncthreads();
  const float4* wi = (const float4*)(Wih + (size_t)tid*384 + 256);
  const float4* c4 = (const float4*)CTX;
  float a0 = 0.f, a1 = 0.f, a2 = 0.f, a3 = 0.f;
  #pragma unroll
  for (int k = 0; k < 32; k++){
    float4 ww = wi[k]; float4 cc = c4[k];
    a0 = fmaf(ww.x, cc.x, a0); a1 = fmaf(ww.y, cc.y, a1);
    a2 = fmaf(ww.z, cc.z, a2); a3 = fmaf(ww.w, cc.w, a3);
  }
  float c = ((a0 + a1) + (a2 + a3));
  for (int t = 0; t < TLEN; t++)
    Gi[t*384 + tid] = At[t*384 + tid] + c;
}

// ---------------- GRU recurrence (R8-identical source; measured 60.0us, VGPR 80) ----------------
__global__ __launch_bounds__(384) void k_gru(const float* __restrict__ Gi,
    const float* __restrict__ Whh, const float* __restrict__ bhh,
    unsigned short* __restrict__ HTt)
{
  __shared__ float GH[384];
  __shared__ alignas(16) float HS[128];
  int tid = threadIdx.x;
  float w[128];
  {
    const float4* wrow = (const float4*)(Whh + (size_t)tid*HIDC);
    #pragma unroll
    for (int k = 0; k < 32; k++){
      float4 v = wrow[k];
      w[4*k+0] = v.x; w[4*k+1] = v.y; w[4*k+2] = v.z; w[4*k+3] = v.w;
    }
  }
  float bh = bhh[tid];
  float hloc = 0.f;
  if (tid < 128) HS[tid] = 0.f;
  __syncthreads();

  const float4* H4 = (const float4*)HS;

  for (int t = 0; t < TLEN; t++){
    float gi0 = 0.f, gi1 = 0.f, gi2 = 0.f;
    if (tid < 128){
      gi0 = Gi[t*384 + tid];
      gi1 = Gi[t*384 + 128 + tid];
      gi2 = Gi[t*384 + 256 + tid];
    }
    float a0 = 0.f, a1 = 0.f, a2 = 0.f, a3 = 0.f;
    #pragma unroll
    for (int q = 0; q < 16; q++){
      float4 ha = H4[2*q];
      float4 hb = H4[2*q+1];
      a0 = fmaf(w[8*q+0], ha.x, a0);
      a1 = fmaf(w[8*q+1], ha.y, a1);
      a2 = fmaf(w[8*q+2], ha.z, a2);
      a3 = fmaf(w[8*q+3], ha.w, a3);
      a0 = fmaf(w[8*q+4], hb.x, a0);
      a1 = fmaf(w[8*q+5], hb.y, a1);
      a2 = fmaf(w[8*q+6], hb.z, a2);
      a3 = fmaf(w[8*q+7], hb.w, a3);
    }
    float acc = ((a0 + a1) + (a2 + a3)) + bh;
    if (tid >= 128) GH[tid] = acc;
    __syncthreads();
    if (tid < 128){
      float gr = gi0 + acc;
      float gz = gi1 + GH[128 + tid];
      float hn = GH[256 + tid];
      float r = sigm(gr);
      float z = sigm(gz);
      float e2 = __expf(2.f*(gi2 + r*hn));
      float cand = __fdividef(e2 - 1.f, e2 + 1.f);
      float hnew = (1.f - z)*cand + z*hloc;
      hloc = hnew;
      HS[tid] = hnew;
      HTt[t*HIDC + tid] = bf16rn(hnew);
    }
    __syncthreads();
  }
}

// ---------------- launch ----------------
extern "C" void kernel_launch(void* const* d_in, const int* in_sizes, int n_in,
                              void* d_out, int out_size, void* d_ws, size_t ws_size,
                              hipStream_t stream)
{
  const int*   x_nodes = (const int*)  d_in[0];
  const int*   eidx    = (const int*)  d_in[1];   // [2][160000]: src then dst
  const int*   tseq    = (const int*)  d_in[2];
  const float* emb     = (const float*)d_in[3];
  const float* W1l     = (const float*)d_in[4];
  const float* W1r     = (const float*)d_in[5];
  const float* att1    = (const float*)d_in[6];
  const float* b1      = (const float*)d_in[7];
  const float* W2l     = (const float*)d_in[8];
  const float* W2r     = (const float*)d_in[9];
  const float* att2    = (const float*)d_in[10];
  const float* b2      = (const float*)d_in[11];
  const float* Wih     = (const float*)d_in[12];
  const float* Whh     = (const float*)d_in[13];
  const float* bih     = (const float*)d_in[14];
  const float* bhh     = (const float*)d_in[15];
  const float* Wout    = (const float*)d_in[16];
  const float* bout    = (const float*)d_in[17];
  float* out = (float*)d_out;
  char*  ws  = (char*)d_ws;

  // workspace layout (bytes), no aliasing
  unsigned char*  xl1f8  = (unsigned char*) (ws);              // 10000*512   =  5,120,000
  unsigned short* xr1b   = (unsigned short*)(ws + 5120000);    // 10000*512*2 = 10,240,000
  unsigned short* h1b    = (unsigned short*)(ws + 15360000);   // 10000*512*2 = 10,240,000
  unsigned short* featsb = (unsigned short*)(ws + 25600000);   // 10000*256*2 =  5,120,000
  unsigned char*  xl2f8  = (unsigned char*) (ws + 30720000);   // 10000*128   =  1,280,000
  unsigned short* xr2b   = (unsigned short*)(ws + 32000000);   // 10000*128*2 =  2,560,000
  unsigned short* Bt1    = (unsigned short*)(ws + 34560000);   // 1024*256*2  =    524,288
  unsigned short* Bt2    = (unsigned short*)(ws + 35084288);   // 256*512*2   =    262,144
  int*   deg    = (int*)(ws + 35346432);                       // 40,000
  int*   offs   = (int*)(ws + 35386432);                       // 40,004
  int*   cursor = (int*)(ws + 35426436);                       // 40,000
  int*   esrc   = (int*)(ws + 35466436);                       // 640,000 (ends 36,106,436)
  float* At     = (float*)(ws + 36106496);                     // 64*384*4 = 98,304 (ends 36,204,800)
  unsigned short* HTt   = (unsigned short*)(ws + 36204800);    // 64*128*2 = 16,384
  unsigned short* Woutb = (unsigned short*)(ws + 36221184);    // 12,865,792 (ends 49,086,976)
  float* ctxp   = (float*)(ws + 49086976);                     // 32*128*4 = 16,384 (ends 49,103,360)
  float* Gi     = (float*)(ws + 49103424);                     // 64*384*4 = 98,304 (ends 49,201,728)

  k_prep<<<PB_AT, 256, 0, stream>>>(x_nodes, emb, featsb, Wout, Woutb,
                                    W1l, W1r, Bt1, W2l, W2r, Bt2,
                                    deg, cursor, ctxp, tseq, Wih, bih, At);

  k_deg    <<<625, 256, 0, stream>>>(eidx + NEDGES, deg);
  k_scan   <<<1,  1024, 0, stream>>>(deg, offs);
  k_scatter<<<625, 256, 0, stream>>>(eidx, eidx + NEDGES, offs, cursor, esrc);

  k_mfma<256><<<dim3(79,8), 256, 0, stream>>>(featsb, Bt1, xl1f8, xr1b, NNODES, 1024);
  k_gat1<<<2500, 256, 0, stream>>>(xl1f8, xr1b, esrc, offs, att1, b1, h1b);

  k_mfma<512><<<dim3(79,2), 256, 0, stream>>>(h1b, Bt2, xl2f8, xr2b, NNODES, 256);
  k_gat2<<<2500, 256, 0, stream>>>(xl2f8, xr2b, esrc, offs, att2, ctxp);

  k_ctx<<<1, 384, 0, stream>>>(At, ctxp, b2, Wih, Gi);
  k_gru<<<1, 384, 0, stream>>>(Gi, Whh, bhh, HTt);

  k_mout<<<393, 256, 0, stream>>>(HTt, Woutb, bout, out);
}